// Round 4
// baseline (1710.093 us; speedup 1.0000x reference)
//
#include <hip/hip_runtime.h>
#include <hip/hip_fp16.h>

#define NB 64
#define NT 1000
#define NH 512
#define NI 32
#define NO 32
#define ALPHA 0.05f
#define NOISE_STD 0.05f

typedef unsigned int uint32;
typedef __attribute__((ext_vector_type(2))) _Float16 half2v;

__device__ __forceinline__ float dot2f(uint32 a, uint32 b, float c) {
#if __has_builtin(__builtin_amdgcn_fdot2)
    return __builtin_amdgcn_fdot2(__builtin_bit_cast(half2v, a),
                                  __builtin_bit_cast(half2v, b), c, false);
#else
    half2v av = __builtin_bit_cast(half2v, a);
    half2v bv = __builtin_bit_cast(half2v, b);
    return c + (float)av[0] * (float)bv[0] + (float)av[1] * (float)bv[1];
#endif
}

// 256 WGs: slice k = bid>>5 (8 slices x 64 cols), pair p = bid&31 (batches 2p,2p+1).
// bid%8 == p%8 -> the 8 slices of one pair land on one XCD (perf heuristic only).
// wsr[b]: 2 parity slots x 512 dwords, dword = (t<<16) | f16bits(r_j).
__global__ __launch_bounds__(512, 1) void rnn_pair_kernel(
    const float* __restrict__ x, const float* __restrict__ noise,
    const float* __restrict__ wi, const float* __restrict__ wrec,
    const float* __restrict__ wout, const float* __restrict__ bias,
    const float* __restrict__ g, const float* __restrict__ tM,
    const float* __restrict__ h0, uint32* __restrict__ wsr,
    float* __restrict__ out)
{
    __shared__ __align__(16) unsigned short wt[64 * 512];   // wrec slice f16, swizzled (64 KB)
    __shared__ __align__(16) unsigned short r16[2][NH];     // full r for A,B (f16)
    __shared__ float red[2][8][64];                         // matvec partials [batch][q][jl]
    __shared__ float xs[2][NI];                             // x_t for A,B

    const int bid = blockIdx.x;
    const int tid = threadIdx.x;
    const int k  = bid >> 5;           // slice 0..7
    const int p  = bid & 31;           // pair 0..31
    const int bA = 2 * p, bB = 2 * p + 1;
    const int jl = tid & 63;           // column within slice / lane
    const int q  = tid >> 6;           // wave 0..7 (= row-block for matvec)
    const int jc = 64 * k + jl;        // owned global column

    // ---- stage wrec slice: cols [64k,64k+64), wave q does rows {q, q+8, ...} ----
    for (int i = q; i < NH; i += 8) {
        float w = wrec[(size_t)i * NH + 64 * k + jl];       // coalesced over jl
        wt[jl * 512 + 8 * ((i >> 3) ^ (jl & 15)) + (i & 7)] =
            __half_as_ushort(__float2half(w));
    }

    // ---- outproj weights in regs: wave q -> batch (q>>2), out col o = 4k + (q&3) ----
    const int obat = (q >> 2) ? bB : bA;
    const int o = 4 * k + (q & 3);
    uint32 wor[4];
    #pragma unroll
    for (int c = 0; c < 4; ++c) {
        float w0 = wout[(size_t)(jl * 8 + 2 * c)     * NO + o];
        float w1 = wout[(size_t)(jl * 8 + 2 * c + 1) * NO + o];
        __half2 hp = __floats2half2_rn(w0, w1);
        wor[c] = *(uint32*)&hp;
    }

    // ---- owner state: tid<64 -> batch A col jc; tid in [64,128) -> batch B col jc ----
    const int ob2 = (tid >> 6) & 1;    // owner batch select (valid tid<128)
    const int myb = ob2 ? bB : bA;
    float h = 0.f, a_inv = 0.f, gj = 0.f, bj = 0.f;
    float wir[NI];
    if (tid < 128) {
        h     = h0[jc];
        a_inv = ALPHA / tM[jc];
        gj    = g[jc];
        bj    = bias[jc];
        #pragma unroll
        for (int i2 = 0; i2 < NI; ++i2) wir[i2] = wi[i2 * NH + jc];
    }
    __syncthreads();

    uint32* wpA0 = wsr + bA * 1024;
    uint32* wpB0 = wsr + bB * 1024;

    for (int t = 0; t < NT; ++t) {
        const int par = (t & 1) * 512;
        uint32* wpA = wpA0 + par;
        uint32* wpB = wpB0 + par;

        // phase 1: publish r(t) for own columns (relaxed agent-scope, self-tagged)
        if (tid < 128) {
            float rv = fmaxf(h, 0.f);
            uint32 val = ((uint32)t << 16) | (uint32)__half_as_ushort(__float2half(rv));
            uint32* wp = ob2 ? wpB : wpA;
            __hip_atomic_store(wp + jc, val, __ATOMIC_RELAXED, __HIP_MEMORY_SCOPE_AGENT);
        }

        // prefetch noise (owners) + stage x_t (waves 2,3)
        float nval = 0.f;
        if (tid < 128)
            nval = noise[((size_t)myb * NT + t) * NH + jc];
        if (q == 2 && jl < NI) xs[0][jl] = x[((size_t)bA * NT + t) * NI + jl];
        if (q == 3 && jl < NI) xs[1][jl] = x[((size_t)bB * NT + t) * NI + jl];

        // phase 2: outproj for t-1 from r16 (shfl-reduce; hides publish latency)
        {
            const uint32* rp = (const uint32*)r16[q >> 2];
            const uint4 rr = *(const uint4*)(rp + jl * 4);   // rows [jl*8, jl*8+8)
            float oa = 0.f;
            oa = dot2f(wor[0], rr.x, oa);
            oa = dot2f(wor[1], rr.y, oa);
            oa = dot2f(wor[2], rr.z, oa);
            oa = dot2f(wor[3], rr.w, oa);
            oa += __shfl_xor(oa, 1, 64);
            oa += __shfl_xor(oa, 2, 64);
            oa += __shfl_xor(oa, 4, 64);
            oa += __shfl_xor(oa, 8, 64);
            oa += __shfl_xor(oa, 16, 64);
            oa += __shfl_xor(oa, 32, 64);
            if (jl == 0 && t > 0)
                out[((size_t)obat * NT + (t - 1)) * NO + o] = oa;
        }
        __syncthreads();   // r16 consumed; xs visible

        // owners: x@wi for this step (runs while others enter the poll)
        float xw = 0.f;
        if (tid < 128) {
            #pragma unroll
            for (int i2 = 0; i2 < NI; ++i2) xw += xs[ob2][i2] * wir[i2];
        }

        // phase 3: poll own dword of both batches until tag==t, deposit to LDS
        {
            const uint32 tg = (uint32)t;
            uint32 vA = __hip_atomic_load(wpA + tid, __ATOMIC_RELAXED, __HIP_MEMORY_SCOPE_AGENT);
            uint32 vB = __hip_atomic_load(wpB + tid, __ATOMIC_RELAXED, __HIP_MEMORY_SCOPE_AGENT);
            while (((vA >> 16) != tg) || ((vB >> 16) != tg)) {
                if ((vA >> 16) != tg)
                    vA = __hip_atomic_load(wpA + tid, __ATOMIC_RELAXED, __HIP_MEMORY_SCOPE_AGENT);
                if ((vB >> 16) != tg)
                    vB = __hip_atomic_load(wpB + tid, __ATOMIC_RELAXED, __HIP_MEMORY_SCOPE_AGENT);
            }
            r16[0][tid] = (unsigned short)(vA & 0xffffu);
            r16[1][tid] = (unsigned short)(vB & 0xffffu);
        }
        __syncthreads();   // full r(t) for A and B ready

        // phase 4: matvec, wt read ONCE, dotted with both batches
        {
            float accA = 0.f, accB = 0.f;
            const uint32* rpA = (const uint32*)r16[0];
            const uint32* rpB = (const uint32*)r16[1];
            #pragma unroll
            for (int mm = 0; mm < 8; ++mm) {
                const int slot = q * 8 + mm;                 // rows [slot*8, slot*8+8)
                const uint4 wv4 = *(const uint4*)(wt + jl * 512 + 8 * (slot ^ (jl & 15)));
                const uint4 ra = *(const uint4*)(rpA + slot * 4);   // wave broadcast
                const uint4 rb = *(const uint4*)(rpB + slot * 4);
                accA = dot2f(wv4.x, ra.x, accA); accA = dot2f(wv4.y, ra.y, accA);
                accA = dot2f(wv4.z, ra.z, accA); accA = dot2f(wv4.w, ra.w, accA);
                accB = dot2f(wv4.x, rb.x, accB); accB = dot2f(wv4.y, rb.y, accB);
                accB = dot2f(wv4.z, rb.z, accB); accB = dot2f(wv4.w, rb.w, accB);
            }
            red[0][q][jl] = accA;
            red[1][q][jl] = accB;
        }
        __syncthreads();

        // phase 5: h update (owners)
        if (tid < 128 && t < NT - 1) {
            float hsum = 0.f;
            #pragma unroll
            for (int qq = 0; qq < 8; ++qq) hsum += red[ob2][qq][jl];   // stride-1 over lanes
            h = h + NOISE_STD * nval + a_inv * (-h + gj * hsum + bj + xw);
        }
    }

    // tail: out row NT-1 from r16 (holds r(NT-1))
    {
        const uint32* rp = (const uint32*)r16[q >> 2];
        const uint4 rr = *(const uint4*)(rp + jl * 4);
        float oa = 0.f;
        oa = dot2f(wor[0], rr.x, oa);
        oa = dot2f(wor[1], rr.y, oa);
        oa = dot2f(wor[2], rr.z, oa);
        oa = dot2f(wor[3], rr.w, oa);
        oa += __shfl_xor(oa, 1, 64);
        oa += __shfl_xor(oa, 2, 64);
        oa += __shfl_xor(oa, 4, 64);
        oa += __shfl_xor(oa, 8, 64);
        oa += __shfl_xor(oa, 16, 64);
        oa += __shfl_xor(oa, 32, 64);
        if (jl == 0)
            out[((size_t)obat * NT + (NT - 1)) * NO + o] = oa;
    }
}

// --------- round-1 fallback (used only if ws is too small) ---------
__global__ __launch_bounds__(1024, 1) void rnn_seq_kernel(
    const float* __restrict__ x, const float* __restrict__ noise,
    const float* __restrict__ wi, const float* __restrict__ wrec,
    const float* __restrict__ wout, const float* __restrict__ bias,
    const float* __restrict__ g, const float* __restrict__ tM,
    const float* __restrict__ h0, float* __restrict__ out)
{
    const int bidx = blockIdx.x;
    const int tid  = threadIdx.x;
    const int j    = tid & (NH - 1);
    const int half = tid >> 9;

    __shared__ float hs[NH];
    __shared__ float rs[NH];
    __shared__ float accb[NH];
    __shared__ float xt[NI];
    __shared__ float red[32][NO + 1];

    float a_inv = 0.f, gj = 0.f, bj = 0.f;
    if (tid < NH) {
        hs[tid] = h0[tid];
        a_inv   = ALPHA / tM[tid];
        gj      = g[tid];
        bj      = bias[tid];
    }
    __syncthreads();

    const int k   = tid & (NO - 1);
    const int seg = tid >> 5;

    for (int t = 0; t < NT; ++t) {
        if (tid < NH) rs[tid] = fmaxf(hs[tid], 0.f);
        if (t < NT - 1 && tid >= NH && tid < NH + NI)
            xt[tid - NH] = x[((size_t)bidx * NT + t) * NI + (tid - NH)];
        __syncthreads();

        float nv = 0.f;
        if (t < NT - 1 && tid < NH)
            nv = noise[((size_t)bidx * NT + t) * NH + tid];

        {
            float pp = 0.f;
            const int base = seg * 16;
            #pragma unroll
            for (int m = 0; m < 16; ++m)
                pp += rs[base + m] * wout[(base + m) * NO + k];
            red[seg][k] = pp;
        }

        float acc = 0.f;
        if (t < NT - 1) {
            const float* wr = wrec + ((size_t)half * 256) * NH + j;
            const int rbase = half * 256;
            #pragma unroll 16
            for (int i = 0; i < 256; ++i)
                acc += rs[rbase + i] * wr[(size_t)i * NH];
            if (half) accb[j] = acc;
        }
        __syncthreads();

        if (t < NT - 1 && tid < NH) {
            float accf = acc + accb[j];
            float xw = 0.f;
            #pragma unroll
            for (int i = 0; i < NI; ++i)
                xw += xt[i] * wi[i * NH + j];
            float hv = hs[j];
            hs[j] = hv + NOISE_STD * nv + a_inv * (-hv + gj * accf + bj + xw);
        }

        if (tid < NO) {
            float s = 0.f;
            #pragma unroll
            for (int sg = 0; sg < 32; ++sg) s += red[sg][tid];
            out[((size_t)bidx * NT + t) * NO + tid] = s;
        }
        __syncthreads();
    }
}

extern "C" void kernel_launch(void* const* d_in, const int* in_sizes, int n_in,
                              void* d_out, int out_size, void* d_ws, size_t ws_size,
                              hipStream_t stream) {
    const float* x     = (const float*)d_in[0];
    const float* noise = (const float*)d_in[1];
    const float* wi    = (const float*)d_in[2];
    const float* wrec  = (const float*)d_in[3];
    const float* wout  = (const float*)d_in[4];
    const float* bias  = (const float*)d_in[5];
    const float* g     = (const float*)d_in[6];
    const float* tM    = (const float*)d_in[7];
    const float* h0    = (const float*)d_in[8];
    float* out = (float*)d_out;

    const size_t wsr_bytes = (size_t)NB * 1024 * 4;   // 262,144

    if (ws_size >= wsr_bytes) {
        uint32* wsr = (uint32*)d_ws;
        // clear tags every replay (0xAAAA can never equal a live tag t<1000)
        hipMemsetAsync(wsr, 0xAA, wsr_bytes, stream);
        rnn_pair_kernel<<<256, 512, 0, stream>>>(x, noise, wi, wrec, wout, bias,
                                                 g, tM, h0, wsr, out);
    } else {
        rnn_seq_kernel<<<NB, 1024, 0, stream>>>(x, noise, wi, wrec, wout, bias, g, tM, h0, out);
    }
}